// Round 9
// baseline (264.714 us; speedup 1.0000x reference)
//
#include <hip/hip_runtime.h>
#include <math.h>

// ContextCluster, fp32, MI355X gfx950 — round 18.
// R17 killed the broadcast theory: masked-dense cc_comb = 83.8us, identical
// to R15's gather (82.7). Five structurally different K2s all cost 82-120us
// vs a <=20us model -> the dependent second kernel ITSELF is the invariant
// cost. R18 deletes it: cc_init writes bias (coalesced, ~5us, handles
// re-poison), cc_main (byte-identical through agg, proven 127.7us) keeps
// proj in LDS and atomically adds its 2-head contribution to out (24
// atomicAdd/thread; all 4 heg contributors share an XCD -> L2-local;
// ~25M conflict-free 4B atomics). No workspace. Numerics: heg-partial
// reorder ~1e-7 vs 4.88e-4 current absmax.

#define TPB 256

__global__ __launch_bounds__(TPB, 8)
void cc_init(const float* __restrict__ bp, float* __restrict__ out)
{
    // block = bb*96 + oc: one 4096-float plane of constant bp[oc]
    const int oc = blockIdx.x % 96;
    const float b = bp[oc];
    const float4 v = make_float4(b, b, b, b);
    float* o = out + (size_t)blockIdx.x * 4096 + threadIdx.x * 4;
    #pragma unroll
    for (int i = 0; i < 4; ++i)
        *(float4*)(o + i*1024) = v;
}

__global__ __launch_bounds__(TPB, 4)
void cc_main(const float* __restrict__ x,
             const float* __restrict__ Wf, const float* __restrict__ bf,
             const float* __restrict__ Wv, const float* __restrict__ bv,
             const float* __restrict__ Wp,
             const float* __restrict__ salpha, const float* __restrict__ sbeta,
             float* __restrict__ out)
{
    // GEMM: Wt = smem[0..4096) [32k][128ch], Xt = smem[4096..6144) [32k][64px]
    // Cluster: fvbuf = smem[0..8320) [128ch][65]; proj overlays smem[0..768)
    __shared__ __align__(16) float smem[8320];
    __shared__ float cfs[2][132], cvs[2][132], swb[2][256], aggs[2][132];
    __shared__ float2 bib[2][64];
    __shared__ float cnts[2][4];

    const int t    = threadIdx.x;
    const int lane = t & 63;
    const int wid  = __builtin_amdgcn_readfirstlane(t >> 6);  // 0..3
    const int tc   = t >> 4;          // 0..15: ch-group (8 ch)
    const int tp   = t & 15;          // px-group (4 consecutive px)
    const int blk  = blockIdx.x;
    // XCD-partitioned decode: XCD = blk&7 = f1 -> x slice L2-resident.
    const int f1   = blk & 7;
    const int f2   = (blk >> 3) & 7;
    const int heg  = (blk >> 6) & 3;  // head-pair 0..3
    const int bb   = blk >> 8;        // batch 0..15

    const float* xb = x + (size_t)bb*96*4096 + (size_t)(f1*8)*64 + f2*8;

    // ---- accumulators (8 ch x 4 px), bias-init ----
    float acc[8][4];
    {
        const float* bsrc = (tc < 8) ? (bf + heg*64 + tc*8)
                                     : (bv + heg*64 + (tc-8)*8);
        float4 b0 = *(const float4*)bsrc;
        float4 b1 = *(const float4*)(bsrc + 4);
        #pragma unroll
        for (int i = 0; i < 4; ++i) {
            acc[0][i]=b0.x; acc[1][i]=b0.y; acc[2][i]=b0.z; acc[3][i]=b0.w;
            acc[4][i]=b1.x; acc[5][i]=b1.y; acc[6][i]=b1.z; acc[7][i]=b1.w;
        }
    }

    // ---- staging decode (t-constant) ----
    // X: 512 float4/chunk, 2/thread
    int xoff[2], xdst[2];
    #pragma unroll
    for (int i = 0; i < 2; ++i) {
        int fl = i*256 + t;
        int kl = fl >> 4, sg = fl & 15;
        xoff[i] = kl*4096 + (sg >> 1)*64 + (sg & 1)*4;
        xdst[i] = 4096 + kl*64 + sg*4;
    }
    // W: 1024 float4/chunk, 4/thread; rr = fl&127 -> 64 consecutive rr per
    // store instr -> 2 lanes/bank (conflict-free). kq wave-uniform.
    int wdst[4];
    const float* wptr[4];
    #pragma unroll
    for (int i = 0; i < 4; ++i) {
        int fl = i*256 + t;
        int rr = fl & 127, kq = fl >> 7;
        wptr[i] = ((rr < 64) ? (Wf + (size_t)(heg*64 + rr)*96)
                             : (Wv + (size_t)(heg*64 + rr - 64)*96)) + kq*4;
        wdst[i] = (kq*4)*128 + rr;
    }

    float4 pxr[2], pwr[4];
    #pragma unroll
    for (int i = 0; i < 2; ++i) pxr[i] = *(const float4*)(xb + xoff[i]);
    #pragma unroll
    for (int i = 0; i < 4; ++i) pwr[i] = *(const float4*)(wptr[i]);
    #pragma unroll
    for (int i = 0; i < 2; ++i) *(float4*)&smem[xdst[i]] = pxr[i];
    #pragma unroll
    for (int i = 0; i < 4; ++i) {
        smem[wdst[i]      ] = pwr[i].x;
        smem[wdst[i] + 128] = pwr[i].y;
        smem[wdst[i] + 256] = pwr[i].z;
        smem[wdst[i] + 384] = pwr[i].w;
    }
    __syncthreads();                  // chunk0 ready

    for (int kc = 0; ; ) {
        if (kc < 64) {                // prefetch next chunk into regs
            #pragma unroll
            for (int i = 0; i < 2; ++i)
                pxr[i] = *(const float4*)(xb + (kc+32)*4096 + xoff[i]);
            #pragma unroll
            for (int i = 0; i < 4; ++i)
                pwr[i] = *(const float4*)(wptr[i] + kc + 32);
        }
        // ---- GEMM chunk: 32 k, 32 FMA/thread/k, 3 LDS b128/thread/k ----
        #pragma unroll 4
        for (int k = 0; k < 32; ++k) {
            float4 wa  = *(const float4*)&smem[k*128 + tc*8];
            float4 wb4 = *(const float4*)&smem[k*128 + tc*8 + 4];
            float4 xq  = *(const float4*)&smem[4096 + k*64 + tp*4];
            float xv[4] = {xq.x, xq.y, xq.z, xq.w};
            #pragma unroll
            for (int i = 0; i < 4; ++i) {
                acc[0][i] = fmaf(wa.x,  xv[i], acc[0][i]);
                acc[1][i] = fmaf(wa.y,  xv[i], acc[1][i]);
                acc[2][i] = fmaf(wa.z,  xv[i], acc[2][i]);
                acc[3][i] = fmaf(wa.w,  xv[i], acc[3][i]);
                acc[4][i] = fmaf(wb4.x, xv[i], acc[4][i]);
                acc[5][i] = fmaf(wb4.y, xv[i], acc[5][i]);
                acc[6][i] = fmaf(wb4.z, xv[i], acc[6][i]);
                acc[7][i] = fmaf(wb4.w, xv[i], acc[7][i]);
            }
        }
        if (kc == 64) break;
        __syncthreads();              // chunk consumed
        #pragma unroll
        for (int i = 0; i < 2; ++i) *(float4*)&smem[xdst[i]] = pxr[i];
        #pragma unroll
        for (int i = 0; i < 4; ++i) {
            smem[wdst[i]      ] = pwr[i].x;
            smem[wdst[i] + 128] = pwr[i].y;
            smem[wdst[i] + 256] = pwr[i].z;
            smem[wdst[i] + 384] = pwr[i].w;
        }
        __syncthreads();              // next chunk ready
        kc += 32;
    }

    // ---- cluster: dump conv result, waves 0/1 handle heads he=wid ----
    const float alpha = salpha[0], beta = sbeta[0];
    __syncthreads();                  // GEMM reads of smem done
    #pragma unroll
    for (int j = 0; j < 8; ++j)
        #pragma unroll
        for (int i2 = 0; i2 < 4; ++i2)
            smem[(tc*8 + j)*65 + tp*4 + i2] = acc[j][i2];
    __syncthreads();

    if (wid < 2) {
        const int he = wid, slot = he;
        // pool: lane -> (m = lane>>4, c0 = (lane&15)*2), 2 centers each
        {
            int m = lane >> 4, c0 = (lane & 15)*2;
            int pw = m >> 1, ph = m & 1;
            #pragma unroll
            for (int cc = 0; cc < 2; ++cc) {
                int c = c0 + cc;
                float mf = -3.402823466e38f, mv = -3.402823466e38f;
                #pragma unroll
                for (int a = 0; a < 4; ++a)
                    #pragma unroll
                    for (int b2 = 0; b2 < 4; ++b2) {
                        int n = (pw*4 + a)*8 + ph*4 + b2;
                        mf = fmaxf(mf, smem[(he*32 + c)*65 + n]);
                        mv = fmaxf(mv, smem[(64 + he*32 + c)*65 + n]);
                    }
                cfs[slot][m*33 + c] = mf;
                cvs[slot][m*33 + c] = mv;
            }
        }
        // sims (lane = n)
        float d0=0,d1=0,d2=0,d3=0,pn=0,cn0=0,cn1=0,cn2=0,cn3=0;
        #pragma unroll 8
        for (int c = 0; c < 32; ++c) {
            float fv = smem[(he*32 + c)*65 + lane];
            float m0 = cfs[slot][c], m1 = cfs[slot][33+c];
            float m2 = cfs[slot][66+c], m3 = cfs[slot][99+c];
            d0 = fmaf(m0, fv, d0); d1 = fmaf(m1, fv, d1);
            d2 = fmaf(m2, fv, d2); d3 = fmaf(m3, fv, d3);
            pn = fmaf(fv, fv, pn);
            cn0 = fmaf(m0, m0, cn0); cn1 = fmaf(m1, m1, cn1);
            cn2 = fmaf(m2, m2, cn2); cn3 = fmaf(m3, m3, cn3);
        }
        float ip = 1.f / fmaxf(sqrtf(pn), 1e-12f);
        float z0 = beta + alpha*(d0*(1.f/fmaxf(sqrtf(cn0),1e-12f))*ip);
        float z1 = beta + alpha*(d1*(1.f/fmaxf(sqrtf(cn1),1e-12f))*ip);
        float z2 = beta + alpha*(d2*(1.f/fmaxf(sqrtf(cn2),1e-12f))*ip);
        float z3 = beta + alpha*(d3*(1.f/fmaxf(sqrtf(cn3),1e-12f))*ip);
        float s0 = 1.f/(1.f + expf(-z0));
        float s1 = 1.f/(1.f + expf(-z1));
        float s2 = 1.f/(1.f + expf(-z2));
        float s3 = 1.f/(1.f + expf(-z3));
        int bi = 0; float bvv = s0;   // first-max tie-break
        if (s1 > bvv) { bvv = s1; bi = 1; }
        if (s2 > bvv) { bvv = s2; bi = 2; }
        if (s3 > bvv) { bvv = s3; bi = 3; }
        int cnt0 = __popcll(__ballot(bi == 0));
        int cnt1 = __popcll(__ballot(bi == 1));
        int cnt2 = __popcll(__ballot(bi == 2));
        int cnt3 = __popcll(__ballot(bi == 3));
        swb[slot][lane]       = (bi==0) ? bvv : 0.f;
        swb[slot][64 + lane]  = (bi==1) ? bvv : 0.f;
        swb[slot][128 + lane] = (bi==2) ? bvv : 0.f;
        swb[slot][192 + lane] = (bi==3) ? bvv : 0.f;
        bib[slot][lane] = make_float2(bvv, (float)bi);
        if (lane == 0) {
            cnts[slot][0] = (float)cnt0; cnts[slot][1] = (float)cnt1;
            cnts[slot][2] = (float)cnt2; cnts[slot][3] = (float)cnt3;
        }
    }
    __syncthreads();

    if (wid >= 2) {
        const int he = wid - 2, slot = he;
        // agg: 2 iters, lane -> (m = it*2 + lane>>5, c = lane&31)
        const int cI = lane & 31;
        #pragma unroll
        for (int it = 0; it < 2; ++it) {
            int mm = it*2 + (lane >> 5);
            float s = 0.f;
            #pragma unroll 8
            for (int n2 = 0; n2 < 64; ++n2)
                s = fmaf(smem[(64 + he*32 + cI)*65 + n2],
                         swb[slot][mm*64 + n2], s);
            aggs[slot][mm*33 + cI] = (s + cvs[slot][mm*33 + cI])
                                   / (cnts[slot][mm] + 1.f);
        }
    }
    __syncthreads();                  // aggs complete

    // ---- proj: pp[he][oc][m] = sum_c Wp[oc][heg*64+he*32+c]*aggs[he][m][c]
    // 768 outputs, 3/thread, into smem[0..768) (f-dump rows 0..11: dead).
    // Writes stride-1 per wave -> 2-way banks, free. Disjoint from agg's
    // v-dump reads [4160..8319) in the previous phase.
    #pragma unroll
    for (int it = 0; it < 3; ++it) {
        int idx = it*256 + t;
        int he  = (idx >= 384) ? 1 : 0;
        int rem = idx - he*384;
        int oc  = rem >> 2, m = rem & 3;
        const float* wp = Wp + (size_t)oc*256 + heg*64 + he*32;
        const float* ag = aggs[he] + m*33;
        float s = 0.f;
        #pragma unroll
        for (int c = 0; c < 32; ++c)
            s = fmaf(wp[c], ag[c], s);
        smem[he*384 + oc*4 + m] = s;
    }
    __syncthreads();                  // proj ready

    // ---- combine: wave wid owns oc0=wid*24, lane = n. Masked-dense FMA
    // (uniform-addr b128 proj reads) + 24 atomicAdd (this block's 2-head
    // contribution; bias written by cc_init; 4 heg blocks share an XCD).
    {
        const int oc0 = wid*24;
        float con[24];
        #pragma unroll
        for (int j = 0; j < 24; ++j) con[j] = 0.f;
        #pragma unroll
        for (int he = 0; he < 2; ++he) {
            float2 sv = bib[he][lane];
            const int bi = (int)sv.y;
            const float s0 = (bi==0) ? sv.x : 0.f;
            const float s1 = (bi==1) ? sv.x : 0.f;
            const float s2 = (bi==2) ? sv.x : 0.f;
            const float s3 = (bi==3) ? sv.x : 0.f;
            const float* pr = &smem[he*384 + oc0*4];   // wave-uniform base
            #pragma unroll
            for (int j = 0; j < 24; ++j) {
                float4 p = *(const float4*)(pr + j*4); // uniform-addr b128
                con[j] = fmaf(p.x, s0, con[j]);
                con[j] = fmaf(p.y, s1, con[j]);
                con[j] = fmaf(p.z, s2, con[j]);
                con[j] = fmaf(p.w, s3, con[j]);
            }
        }
        // lane = n -> out[bb][oc][f1*8 + n>>3][f2*8 + (n&7)]
        const int r = lane >> 3, hh = lane & 7;
        const size_t ob = (size_t)bb*96*4096
                        + (size_t)(f1*8 + r)*64 + f2*8 + hh;
        #pragma unroll
        for (int j = 0; j < 24; ++j)
            atomicAdd(&out[ob + (size_t)(oc0 + j)*4096], con[j]);
    }
}

extern "C" void kernel_launch(void* const* d_in, const int* in_sizes, int n_in,
                              void* d_out, int out_size, void* d_ws, size_t ws_size,
                              hipStream_t stream) {
    (void)in_sizes; (void)n_in; (void)out_size; (void)d_ws; (void)ws_size;
    cc_init<<<dim3(1536), dim3(TPB), 0, stream>>>(
        (const float*)d_in[6],  // bp
        (float*)d_out);
    cc_main<<<dim3(4096), dim3(TPB), 0, stream>>>(
        (const float*)d_in[0],  // x
        (const float*)d_in[1],  // Wf
        (const float*)d_in[2],  // bf
        (const float*)d_in[3],  // Wv
        (const float*)d_in[4],  // bv
        (const float*)d_in[5],  // Wp
        (const float*)d_in[7],  // sim_alpha
        (const float*)d_in[8],  // sim_beta
        (float*)d_out);
}

// Round 10
// 213.214 us; speedup vs baseline: 1.2415x; 1.2415x over previous
//
#include <hip/hip_runtime.h>
#include <math.h>

// ContextCluster, fp32, MI355X gfx950 — round 19.
// R18 calibration: total = kernels + ~72us FIXED harness overhead (launch +
// re-poison). cc_comb was ~11us all along (the "83us" was overhead
// misattribution; 167us top-5 instances were cold dispatch 0). Real lever:
// cc_main 127.7us vs 41us FMA floor — LDS-read-pipe-bound (16 waves x 3
// ds_read_b128 = 576 cyc/k vs 256 VALU). R19: 2-fold blocks (128ch x 128px),
// 8x8 thread tile -> 4 b128 per 64 FMA (LDS cyc/FMA -33%, GEMM LDS wall
// 92 -> 61us). Cluster = R15/R17 code byte-identical, run twice (half
// threads dump per round); total cluster work unchanged. All FMA chains
// k-ascending -> bit-identical output. cc_comb = R17 verbatim (passed).

#define TPB 256

__global__ __launch_bounds__(TPB, 4)
void cc_main(const float* __restrict__ x,
             const float* __restrict__ Wf, const float* __restrict__ bf,
             const float* __restrict__ Wv, const float* __restrict__ bv,
             const float* __restrict__ Wp,
             const float* __restrict__ salpha, const float* __restrict__ sbeta,
             float* __restrict__ cd)
{
    // GEMM: W[16k][128ch]@0, X[16k][128px]@2048 (16KB).
    // Cluster (overlays): fv[128ch][65] = 8320 floats (33.3KB).
    __shared__ __align__(16) float smem[8320];
    __shared__ float cfs[2][132], cvs[2][132], swb[2][256], aggs[2][132];
    __shared__ float2 bib[2][64];
    __shared__ float cnts[2][4];

    const int t    = threadIdx.x;
    const int lane = t & 63;
    const int wid  = __builtin_amdgcn_readfirstlane(t >> 6);  // 0..3
    const int cg   = t >> 4;          // 0..15: ch-group (8 ch)
    const int pg   = t & 15;          // 0..15: px-group (8 px; fold = pg>>3)
    const int blk  = blockIdx.x;      // 0..2047
    // XCD-partitioned: blk&7 = f1 -> x slice L2-resident (R10-verified).
    const int f1   = blk & 7;
    const int f2p  = (blk >> 3) & 3;  // fold-pair: f2 = f2p*2 + fl
    const int heg  = (blk >> 5) & 3;  // head-pair
    const int bb   = blk >> 7;        // batch

    const float* xb = x + (size_t)bb*96*4096 + (size_t)(f1*8)*64 + f2p*16;

    // ---- accumulators 8ch x 8px, bias-init ----
    float acc[8][8];
    {
        const float* bsrc = ((cg < 8) ? bf : bv) + heg*64 + (cg & 7)*8;
        float4 b0 = *(const float4*)bsrc, b1 = *(const float4*)(bsrc + 4);
        float bj[8] = {b0.x,b0.y,b0.z,b0.w,b1.x,b1.y,b1.z,b1.w};
        #pragma unroll
        for (int j = 0; j < 8; ++j)
            #pragma unroll
            for (int i = 0; i < 8; ++i) acc[j][i] = bj[j];
    }

    // ---- staging decode (chunk = 16 k) ----
    // X: 512 f4/chunk, 2/thread. p4 = global px*? : cols f4-clean.
    int xoff[2], xdst[2];
    #pragma unroll
    for (int i = 0; i < 2; ++i) {
        int fl = i*256 + t;
        int kl = fl >> 5, p4 = (fl & 31)*4;
        xoff[i] = kl*4096 + ((p4 & 63) >> 3)*64 + (p4 >> 6)*8 + (p4 & 7);
        xdst[i] = 2048 + kl*128 + p4;
    }
    // W: 512 f4/chunk, 2/thread; rr consecutive per store -> 2-way free.
    int wdst[2]; const float* wptr[2];
    #pragma unroll
    for (int i = 0; i < 2; ++i) {
        int fl = i*256 + t;
        int rr = fl & 127, kq = fl >> 7;          // kq 0..3
        wptr[i] = ((rr < 64) ? (Wf + (size_t)(heg*64 + rr)*96)
                             : (Wv + (size_t)(heg*64 + rr - 64)*96)) + kq*4;
        wdst[i] = (kq*4)*128 + rr;
    }

    float4 pxr[2], pwr[2];
    #pragma unroll
    for (int i = 0; i < 2; ++i) pxr[i] = *(const float4*)(xb + xoff[i]);
    #pragma unroll
    for (int i = 0; i < 2; ++i) pwr[i] = *(const float4*)(wptr[i]);
    #pragma unroll
    for (int i = 0; i < 2; ++i) *(float4*)&smem[xdst[i]] = pxr[i];
    #pragma unroll
    for (int i = 0; i < 2; ++i) {
        smem[wdst[i]      ] = pwr[i].x;
        smem[wdst[i] + 128] = pwr[i].y;
        smem[wdst[i] + 256] = pwr[i].z;
        smem[wdst[i] + 384] = pwr[i].w;
    }
    __syncthreads();                  // chunk0 ready

    for (int kc = 0; ; ) {
        if (kc < 80) {                // prefetch next 16-k chunk
            #pragma unroll
            for (int i = 0; i < 2; ++i)
                pxr[i] = *(const float4*)(xb + (kc+16)*4096 + xoff[i]);
            #pragma unroll
            for (int i = 0; i < 2; ++i)
                pwr[i] = *(const float4*)(wptr[i] + kc + 16);
        }
        // ---- GEMM chunk: 16 k, 64 FMA/thread/k, 4 LDS b128/thread/k ----
        #pragma unroll 4
        for (int k = 0; k < 16; ++k) {
            float4 wa = *(const float4*)&smem[k*128 + cg*8];
            float4 wb = *(const float4*)&smem[k*128 + cg*8 + 4];
            float4 xa = *(const float4*)&smem[2048 + k*128 + pg*8];
            float4 xc = *(const float4*)&smem[2048 + k*128 + pg*8 + 4];
            float wv[8] = {wa.x,wa.y,wa.z,wa.w,wb.x,wb.y,wb.z,wb.w};
            float xv[8] = {xa.x,xa.y,xa.z,xa.w,xc.x,xc.y,xc.z,xc.w};
            #pragma unroll
            for (int j = 0; j < 8; ++j)
                #pragma unroll
                for (int i = 0; i < 8; ++i)
                    acc[j][i] = fmaf(wv[j], xv[i], acc[j][i]);
        }
        if (kc == 80) break;
        __syncthreads();              // chunk consumed
        #pragma unroll
        for (int i = 0; i < 2; ++i) *(float4*)&smem[xdst[i]] = pxr[i];
        #pragma unroll
        for (int i = 0; i < 2; ++i) {
            smem[wdst[i]      ] = pwr[i].x;
            smem[wdst[i] + 128] = pwr[i].y;
            smem[wdst[i] + 256] = pwr[i].z;
            smem[wdst[i] + 384] = pwr[i].w;
        }
        __syncthreads();              // next chunk ready
        kc += 16;
    }

    // ---- cluster: 2 rounds (fold fl of the pair), R15 code per round ----
    const float alpha = salpha[0], beta = sbeta[0];

    for (int fl = 0; fl < 2; ++fl) {
        __syncthreads();              // GEMM/prev-round LDS reads done
        if ((pg >> 3) == fl) {        // dump this fold: 64 scalars/thread
            const int nb = (pg & 7)*8;
            #pragma unroll
            for (int j = 0; j < 8; ++j)
                #pragma unroll
                for (int i = 0; i < 8; ++i)
                    smem[(cg*8 + j)*65 + nb + i] = acc[j][i];
        }
        __syncthreads();

        if (wid < 2) {
            const int he = wid, slot = he;
            // pool: lane -> (m = lane>>4, c0 = (lane&15)*2), 2 centers each
            {
                int m = lane >> 4, c0 = (lane & 15)*2;
                int pw = m >> 1, ph = m & 1;
                #pragma unroll
                for (int cc = 0; cc < 2; ++cc) {
                    int c = c0 + cc;
                    float mf = -3.402823466e38f, mv = -3.402823466e38f;
                    #pragma unroll
                    for (int a = 0; a < 4; ++a)
                        #pragma unroll
                        for (int b2 = 0; b2 < 4; ++b2) {
                            int n = (pw*4 + a)*8 + ph*4 + b2;
                            mf = fmaxf(mf, smem[(he*32 + c)*65 + n]);
                            mv = fmaxf(mv, smem[(64 + he*32 + c)*65 + n]);
                        }
                    cfs[slot][m*33 + c] = mf;
                    cvs[slot][m*33 + c] = mv;
                }
            }
            // sims (lane = n)
            float d0=0,d1=0,d2=0,d3=0,pn=0,cn0=0,cn1=0,cn2=0,cn3=0;
            #pragma unroll 8
            for (int c = 0; c < 32; ++c) {
                float fv = smem[(he*32 + c)*65 + lane];
                float m0 = cfs[slot][c], m1 = cfs[slot][33+c];
                float m2 = cfs[slot][66+c], m3 = cfs[slot][99+c];
                d0 = fmaf(m0, fv, d0); d1 = fmaf(m1, fv, d1);
                d2 = fmaf(m2, fv, d2); d3 = fmaf(m3, fv, d3);
                pn = fmaf(fv, fv, pn);
                cn0 = fmaf(m0, m0, cn0); cn1 = fmaf(m1, m1, cn1);
                cn2 = fmaf(m2, m2, cn2); cn3 = fmaf(m3, m3, cn3);
            }
            float ip = 1.f / fmaxf(sqrtf(pn), 1e-12f);
            float z0 = beta + alpha*(d0*(1.f/fmaxf(sqrtf(cn0),1e-12f))*ip);
            float z1 = beta + alpha*(d1*(1.f/fmaxf(sqrtf(cn1),1e-12f))*ip);
            float z2 = beta + alpha*(d2*(1.f/fmaxf(sqrtf(cn2),1e-12f))*ip);
            float z3 = beta + alpha*(d3*(1.f/fmaxf(sqrtf(cn3),1e-12f))*ip);
            float s0 = 1.f/(1.f + expf(-z0));
            float s1 = 1.f/(1.f + expf(-z1));
            float s2 = 1.f/(1.f + expf(-z2));
            float s3 = 1.f/(1.f + expf(-z3));
            int bi = 0; float bvv = s0;   // first-max tie-break
            if (s1 > bvv) { bvv = s1; bi = 1; }
            if (s2 > bvv) { bvv = s2; bi = 2; }
            if (s3 > bvv) { bvv = s3; bi = 3; }
            int cnt0 = __popcll(__ballot(bi == 0));
            int cnt1 = __popcll(__ballot(bi == 1));
            int cnt2 = __popcll(__ballot(bi == 2));
            int cnt3 = __popcll(__ballot(bi == 3));
            swb[slot][lane]       = (bi==0) ? bvv : 0.f;
            swb[slot][64 + lane]  = (bi==1) ? bvv : 0.f;
            swb[slot][128 + lane] = (bi==2) ? bvv : 0.f;
            swb[slot][192 + lane] = (bi==3) ? bvv : 0.f;
            bib[slot][lane] = make_float2(bvv, (float)bi);
            if (lane == 0) {
                cnts[slot][0] = (float)cnt0; cnts[slot][1] = (float)cnt1;
                cnts[slot][2] = (float)cnt2; cnts[slot][3] = (float)cnt3;
            }
        }
        __syncthreads();

        const int fold = f1*8 + f2p*2 + fl;
        float* tb = cd + ((size_t)(bb*64 + fold))*4096;

        if (wid >= 2) {
            const int he = wid - 2, slot = he;
            // agg: 2 iters, lane -> (m = it*2 + lane>>5, c = lane&31)
            const int cI = lane & 31;
            #pragma unroll
            for (int it = 0; it < 2; ++it) {
                int mm = it*2 + (lane >> 5);
                float s = 0.f;
                #pragma unroll 8
                for (int n2 = 0; n2 < 64; ++n2)
                    s = fmaf(smem[(64 + he*32 + cI)*65 + n2],
                             swb[slot][mm*64 + n2], s);
                aggs[slot][mm*33 + cI] = (s + cvs[slot][mm*33 + cI])
                                       / (cnts[slot][mm] + 1.f);
            }
            // sel write: (bvv, bi) per pixel
            float2 b2 = bib[slot][lane];
            *(float2*)&tb[3072 + (heg*2 + he)*128 + lane*2] = b2;
        }
        __syncthreads();              // aggs complete

        // proj: proj_he[oc][m] = sum_c Wp[oc][heg*64+he*32+c]*aggs[he][m][c]
        #pragma unroll
        for (int it = 0; it < 3; ++it) {
            int idx = it*256 + t;
            int he  = (idx >= 384) ? 1 : 0;
            int rem = idx - he*384;
            int oc  = rem >> 2, m = rem & 3;
            const float* wp = Wp + (size_t)oc*256 + heg*64 + he*32;
            const float* ag = aggs[he] + m*33;
            float s = 0.f;
            #pragma unroll
            for (int c = 0; c < 32; ++c)
                s = fmaf(wp[c], ag[c], s);
            tb[(heg*2 + he)*384 + oc*4 + m] = s;
        }
    }
}

// K2-lite (masked dense, R17 verbatim): out[oc][n] = bp[oc]
//   + sum_{he,m} proj_he[oc][m] * ((bi_n==m)?bvv_n:0).
// 1024 blocks (bb,fold), 256 threads; wave = 24 oc, lane = px n.
__global__ __launch_bounds__(TPB, 8)
void cc_comb(const float* __restrict__ cd, const float* __restrict__ bp,
             float* __restrict__ out)
{
    __shared__ __align__(16) float ld[4096];   // proj @0, sel @3072
    const int t    = threadIdx.x;
    const int lane = t & 63;
    const int wid  = __builtin_amdgcn_readfirstlane(t >> 6);  // oc-block
    const int blk  = blockIdx.x;       // 0..1023
    const int f1   = blk & 7;
    const int f2   = (blk >> 3) & 7;
    const int bb   = blk >> 6;
    const float* tb = cd + ((size_t)(bb*64 + f1*8 + f2))*4096;

    // stage: 1024 f4, 4/thread, identity
    #pragma unroll
    for (int i = 0; i < 4; ++i) {
        float4 v = *(const float4*)(tb + (t*4 + i)*4);
        *(float4*)&ld[(t*4 + i)*4] = v;
    }
    __syncthreads();

    const int oc0 = wid*24;
    float acc[24];
    #pragma unroll
    for (int j = 0; j < 24; j += 4) {
        float4 b = *(const float4*)(bp + oc0 + j);
        acc[j]=b.x; acc[j+1]=b.y; acc[j+2]=b.z; acc[j+3]=b.w;
    }

    #pragma unroll
    for (int he = 0; he < 8; ++he) {
        float2 sv = *(const float2*)&ld[3072 + he*128 + lane*2];
        const int bi = (int)sv.y;
        const float s0 = (bi==0) ? sv.x : 0.f;
        const float s1 = (bi==1) ? sv.x : 0.f;
        const float s2 = (bi==2) ? sv.x : 0.f;
        const float s3 = (bi==3) ? sv.x : 0.f;
        const float* pr = &ld[he*384 + oc0*4];   // wave-uniform base
        #pragma unroll
        for (int j = 0; j < 24; ++j) {
            float4 p = *(const float4*)(pr + j*4);  // uniform-addr b128
            acc[j] = fmaf(p.x, s0, acc[j]);
            acc[j] = fmaf(p.y, s1, acc[j]);
            acc[j] = fmaf(p.z, s2, acc[j]);
            acc[j] = fmaf(p.w, s3, acc[j]);
        }
    }

    // epilogue: lane = n -> out[bb][oc][f1*8 + n>>3][f2*8 + (n&7)]
    const int r = lane >> 3, hh = lane & 7;
    const size_t ob = (size_t)bb*96*4096 + (size_t)(f1*8 + r)*64 + f2*8 + hh;
    #pragma unroll
    for (int j = 0; j < 24; ++j)
        out[ob + (size_t)(oc0 + j)*4096] = acc[j];
}

extern "C" void kernel_launch(void* const* d_in, const int* in_sizes, int n_in,
                              void* d_out, int out_size, void* d_ws, size_t ws_size,
                              hipStream_t stream) {
    (void)in_sizes; (void)n_in; (void)out_size; (void)ws_size;
    float* cd = (float*)d_ws;   // 1024 tiles x 4096 floats = 16 MiB
    cc_main<<<dim3(2048), dim3(TPB), 0, stream>>>(
        (const float*)d_in[0],  // x
        (const float*)d_in[1],  // Wf
        (const float*)d_in[2],  // bf
        (const float*)d_in[3],  // Wv
        (const float*)d_in[4],  // bv
        (const float*)d_in[5],  // Wp
        (const float*)d_in[7],  // sim_alpha
        (const float*)d_in[8],  // sim_beta
        cd);
    cc_comb<<<dim3(1024), dim3(TPB), 0, stream>>>(
        cd,
        (const float*)d_in[6],  // bp
        (float*)d_out);
}

// Round 11
// 210.713 us; speedup vs baseline: 1.2563x; 1.0119x over previous
//
#include <hip/hip_runtime.h>
#include <math.h>

// ContextCluster, fp32, MI355X gfx950 — round 20.
// R19 post-mortem: 8x8 retile was the right lever but its X-tile read
// (stride 32B across 16 pg) was a 4-way bank conflict -> SQ_LDS_BANK_CONFLICT
// 2.36M -> 10.75M, cc_main 127.7 -> 138.3us. R20 keeps the 8x8 tile and
// fixes the layout: X groups padded to 12 floats (group g at k*192+g*12,
// 16B-aligned) -> read banks (12pg)%32 = 8 quads x 2 pg = 2-way = FREE
// (m136). W reads remain 16-lane broadcast (free). All arithmetic orders
// byte-identical to R19 -> bit-identical output. cc_comb = R17 verbatim.

#define TPB 256

__global__ __launch_bounds__(TPB, 4)
void cc_main(const float* __restrict__ x,
             const float* __restrict__ Wf, const float* __restrict__ bf,
             const float* __restrict__ Wv, const float* __restrict__ bv,
             const float* __restrict__ Wp,
             const float* __restrict__ salpha, const float* __restrict__ sbeta,
             float* __restrict__ cd)
{
    // GEMM: W[16k][128ch]@0, X[16k][16grp x 12]@2048 (20.5KB).
    // Cluster (overlays): fv[128ch][65] = 8320 floats (33.3KB).
    __shared__ __align__(16) float smem[8320];
    __shared__ float cfs[2][132], cvs[2][132], swb[2][256], aggs[2][132];
    __shared__ float2 bib[2][64];
    __shared__ float cnts[2][4];

    const int t    = threadIdx.x;
    const int lane = t & 63;
    const int wid  = __builtin_amdgcn_readfirstlane(t >> 6);  // 0..3
    const int cg   = t >> 4;          // 0..15: ch-group (8 ch)
    const int pg   = t & 15;          // 0..15: px-group (8 px; fold = pg>>3)
    const int blk  = blockIdx.x;      // 0..2047
    // XCD-partitioned: blk&7 = f1 -> x slice L2-resident (R10-verified).
    const int f1   = blk & 7;
    const int f2p  = (blk >> 3) & 3;  // fold-pair: f2 = f2p*2 + fl
    const int heg  = (blk >> 5) & 3;  // head-pair
    const int bb   = blk >> 7;        // batch

    const float* xb = x + (size_t)bb*96*4096 + (size_t)(f1*8)*64 + f2p*16;

    // ---- accumulators 8ch x 8px, bias-init ----
    float acc[8][8];
    {
        const float* bsrc = ((cg < 8) ? bf : bv) + heg*64 + (cg & 7)*8;
        float4 b0 = *(const float4*)bsrc, b1 = *(const float4*)(bsrc + 4);
        float bj[8] = {b0.x,b0.y,b0.z,b0.w,b1.x,b1.y,b1.z,b1.w};
        #pragma unroll
        for (int j = 0; j < 8; ++j)
            #pragma unroll
            for (int i = 0; i < 8; ++i) acc[j][i] = bj[j];
    }

    // ---- staging decode (chunk = 16 k) ----
    // X: 512 f4/chunk, 2/thread. px p4 = (fl&31)*4; group g = p4>>3,
    // half h = (p4>>2)&1; padded dst = 2048 + kl*192 + g*12 + h*4.
    int xoff[2], xdst[2];
    #pragma unroll
    for (int i = 0; i < 2; ++i) {
        int fl = i*256 + t;
        int kl = fl >> 5, p4 = (fl & 31)*4;
        xoff[i] = kl*4096 + ((p4 & 63) >> 3)*64 + (p4 >> 6)*8 + (p4 & 7);
        xdst[i] = 2048 + kl*192 + (p4 >> 3)*12 + ((p4 >> 2) & 1)*4;
    }
    // W: 512 f4/chunk, 2/thread; rr consecutive per store -> 2-way free.
    int wdst[2]; const float* wptr[2];
    #pragma unroll
    for (int i = 0; i < 2; ++i) {
        int fl = i*256 + t;
        int rr = fl & 127, kq = fl >> 7;          // kq 0..3
        wptr[i] = ((rr < 64) ? (Wf + (size_t)(heg*64 + rr)*96)
                             : (Wv + (size_t)(heg*64 + rr - 64)*96)) + kq*4;
        wdst[i] = (kq*4)*128 + rr;
    }

    float4 pxr[2], pwr[2];
    #pragma unroll
    for (int i = 0; i < 2; ++i) pxr[i] = *(const float4*)(xb + xoff[i]);
    #pragma unroll
    for (int i = 0; i < 2; ++i) pwr[i] = *(const float4*)(wptr[i]);
    #pragma unroll
    for (int i = 0; i < 2; ++i) *(float4*)&smem[xdst[i]] = pxr[i];
    #pragma unroll
    for (int i = 0; i < 2; ++i) {
        smem[wdst[i]      ] = pwr[i].x;
        smem[wdst[i] + 128] = pwr[i].y;
        smem[wdst[i] + 256] = pwr[i].z;
        smem[wdst[i] + 384] = pwr[i].w;
    }
    __syncthreads();                  // chunk0 ready

    for (int kc = 0; ; ) {
        if (kc < 80) {                // prefetch next 16-k chunk
            #pragma unroll
            for (int i = 0; i < 2; ++i)
                pxr[i] = *(const float4*)(xb + (kc+16)*4096 + xoff[i]);
            #pragma unroll
            for (int i = 0; i < 2; ++i)
                pwr[i] = *(const float4*)(wptr[i] + kc + 16);
        }
        // ---- GEMM chunk: 16 k, 64 FMA/thread/k, 4 LDS b128/thread/k ----
        // W reads: 16-lane same-addr broadcast (free). X reads: padded
        // groups -> 2 pg per bank-quad = 2-way (free).
        #pragma unroll 4
        for (int k = 0; k < 16; ++k) {
            float4 wa = *(const float4*)&smem[k*128 + cg*8];
            float4 wb = *(const float4*)&smem[k*128 + cg*8 + 4];
            float4 xa = *(const float4*)&smem[2048 + k*192 + pg*12];
            float4 xc = *(const float4*)&smem[2048 + k*192 + pg*12 + 4];
            float wv[8] = {wa.x,wa.y,wa.z,wa.w,wb.x,wb.y,wb.z,wb.w};
            float xv[8] = {xa.x,xa.y,xa.z,xa.w,xc.x,xc.y,xc.z,xc.w};
            #pragma unroll
            for (int j = 0; j < 8; ++j)
                #pragma unroll
                for (int i = 0; i < 8; ++i)
                    acc[j][i] = fmaf(wv[j], xv[i], acc[j][i]);
        }
        if (kc == 80) break;
        __syncthreads();              // chunk consumed
        #pragma unroll
        for (int i = 0; i < 2; ++i) *(float4*)&smem[xdst[i]] = pxr[i];
        #pragma unroll
        for (int i = 0; i < 2; ++i) {
            smem[wdst[i]      ] = pwr[i].x;
            smem[wdst[i] + 128] = pwr[i].y;
            smem[wdst[i] + 256] = pwr[i].z;
            smem[wdst[i] + 384] = pwr[i].w;
        }
        __syncthreads();              // next chunk ready
        kc += 16;
    }

    // ---- cluster: 2 rounds (fold fl of the pair), R15 code per round ----
    const float alpha = salpha[0], beta = sbeta[0];

    for (int fl = 0; fl < 2; ++fl) {
        __syncthreads();              // GEMM/prev-round LDS reads done
        if ((pg >> 3) == fl) {        // dump this fold: 64 scalars/thread
            const int nb = (pg & 7)*8;
            #pragma unroll
            for (int j = 0; j < 8; ++j)
                #pragma unroll
                for (int i = 0; i < 8; ++i)
                    smem[(cg*8 + j)*65 + nb + i] = acc[j][i];
        }
        __syncthreads();

        if (wid < 2) {
            const int he = wid, slot = he;
            // pool: lane -> (m = lane>>4, c0 = (lane&15)*2), 2 centers each
            {
                int m = lane >> 4, c0 = (lane & 15)*2;
                int pw = m >> 1, ph = m & 1;
                #pragma unroll
                for (int cc = 0; cc < 2; ++cc) {
                    int c = c0 + cc;
                    float mf = -3.402823466e38f, mv = -3.402823466e38f;
                    #pragma unroll
                    for (int a = 0; a < 4; ++a)
                        #pragma unroll
                        for (int b2 = 0; b2 < 4; ++b2) {
                            int n = (pw*4 + a)*8 + ph*4 + b2;
                            mf = fmaxf(mf, smem[(he*32 + c)*65 + n]);
                            mv = fmaxf(mv, smem[(64 + he*32 + c)*65 + n]);
                        }
                    cfs[slot][m*33 + c] = mf;
                    cvs[slot][m*33 + c] = mv;
                }
            }
            // sims (lane = n)
            float d0=0,d1=0,d2=0,d3=0,pn=0,cn0=0,cn1=0,cn2=0,cn3=0;
            #pragma unroll 8
            for (int c = 0; c < 32; ++c) {
                float fv = smem[(he*32 + c)*65 + lane];
                float m0 = cfs[slot][c], m1 = cfs[slot][33+c];
                float m2 = cfs[slot][66+c], m3 = cfs[slot][99+c];
                d0 = fmaf(m0, fv, d0); d1 = fmaf(m1, fv, d1);
                d2 = fmaf(m2, fv, d2); d3 = fmaf(m3, fv, d3);
                pn = fmaf(fv, fv, pn);
                cn0 = fmaf(m0, m0, cn0); cn1 = fmaf(m1, m1, cn1);
                cn2 = fmaf(m2, m2, cn2); cn3 = fmaf(m3, m3, cn3);
            }
            float ip = 1.f / fmaxf(sqrtf(pn), 1e-12f);
            float z0 = beta + alpha*(d0*(1.f/fmaxf(sqrtf(cn0),1e-12f))*ip);
            float z1 = beta + alpha*(d1*(1.f/fmaxf(sqrtf(cn1),1e-12f))*ip);
            float z2 = beta + alpha*(d2*(1.f/fmaxf(sqrtf(cn2),1e-12f))*ip);
            float z3 = beta + alpha*(d3*(1.f/fmaxf(sqrtf(cn3),1e-12f))*ip);
            float s0 = 1.f/(1.f + expf(-z0));
            float s1 = 1.f/(1.f + expf(-z1));
            float s2 = 1.f/(1.f + expf(-z2));
            float s3 = 1.f/(1.f + expf(-z3));
            int bi = 0; float bvv = s0;   // first-max tie-break
            if (s1 > bvv) { bvv = s1; bi = 1; }
            if (s2 > bvv) { bvv = s2; bi = 2; }
            if (s3 > bvv) { bvv = s3; bi = 3; }
            int cnt0 = __popcll(__ballot(bi == 0));
            int cnt1 = __popcll(__ballot(bi == 1));
            int cnt2 = __popcll(__ballot(bi == 2));
            int cnt3 = __popcll(__ballot(bi == 3));
            swb[slot][lane]       = (bi==0) ? bvv : 0.f;
            swb[slot][64 + lane]  = (bi==1) ? bvv : 0.f;
            swb[slot][128 + lane] = (bi==2) ? bvv : 0.f;
            swb[slot][192 + lane] = (bi==3) ? bvv : 0.f;
            bib[slot][lane] = make_float2(bvv, (float)bi);
            if (lane == 0) {
                cnts[slot][0] = (float)cnt0; cnts[slot][1] = (float)cnt1;
                cnts[slot][2] = (float)cnt2; cnts[slot][3] = (float)cnt3;
            }
        }
        __syncthreads();

        const int fold = f1*8 + f2p*2 + fl;
        float* tb = cd + ((size_t)(bb*64 + fold))*4096;

        if (wid >= 2) {
            const int he = wid - 2, slot = he;
            // agg: 2 iters, lane -> (m = it*2 + lane>>5, c = lane&31)
            const int cI = lane & 31;
            #pragma unroll
            for (int it = 0; it < 2; ++it) {
                int mm = it*2 + (lane >> 5);
                float s = 0.f;
                #pragma unroll 8
                for (int n2 = 0; n2 < 64; ++n2)
                    s = fmaf(smem[(64 + he*32 + cI)*65 + n2],
                             swb[slot][mm*64 + n2], s);
                aggs[slot][mm*33 + cI] = (s + cvs[slot][mm*33 + cI])
                                       / (cnts[slot][mm] + 1.f);
            }
            // sel write: (bvv, bi) per pixel
            float2 b2 = bib[slot][lane];
            *(float2*)&tb[3072 + (heg*2 + he)*128 + lane*2] = b2;
        }
        __syncthreads();              // aggs complete

        // proj: proj_he[oc][m] = sum_c Wp[oc][heg*64+he*32+c]*aggs[he][m][c]
        #pragma unroll
        for (int it = 0; it < 3; ++it) {
            int idx = it*256 + t;
            int he  = (idx >= 384) ? 1 : 0;
            int rem = idx - he*384;
            int oc  = rem >> 2, m = rem & 3;
            const float* wp = Wp + (size_t)oc*256 + heg*64 + he*32;
            const float* ag = aggs[he] + m*33;
            float s = 0.f;
            #pragma unroll
            for (int c = 0; c < 32; ++c)
                s = fmaf(wp[c], ag[c], s);
            tb[(heg*2 + he)*384 + oc*4 + m] = s;
        }
    }
}

// K2-lite (masked dense, R17 verbatim): out[oc][n] = bp[oc]
//   + sum_{he,m} proj_he[oc][m] * ((bi_n==m)?bvv_n:0).
// 1024 blocks (bb,fold), 256 threads; wave = 24 oc, lane = px n.
__global__ __launch_bounds__(TPB, 8)
void cc_comb(const float* __restrict__ cd, const float* __restrict__ bp,
             float* __restrict__ out)
{
    __shared__ __align__(16) float ld[4096];   // proj @0, sel @3072
    const int t    = threadIdx.x;
    const int lane = t & 63;
    const int wid  = __builtin_amdgcn_readfirstlane(t >> 6);  // oc-block
    const int blk  = blockIdx.x;       // 0..1023
    const int f1   = blk & 7;
    const int f2   = (blk >> 3) & 7;
    const int bb   = blk >> 6;
    const float* tb = cd + ((size_t)(bb*64 + f1*8 + f2))*4096;

    // stage: 1024 f4, 4/thread, identity
    #pragma unroll
    for (int i = 0; i < 4; ++i) {
        float4 v = *(const float4*)(tb + (t*4 + i)*4);
        *(float4*)&ld[(t*4 + i)*4] = v;
    }
    __syncthreads();

    const int oc0 = wid*24;
    float acc[24];
    #pragma unroll
    for (int j = 0; j < 24; j += 4) {
        float4 b = *(const float4*)(bp + oc0 + j);
        acc[j]=b.x; acc[j+1]=b.y; acc[j+2]=b.z; acc[j+3]=b.w;
    }

    #pragma unroll
    for (int he = 0; he < 8; ++he) {
        float2 sv = *(const float2*)&ld[3072 + he*128 + lane*2];
        const int bi = (int)sv.y;
        const float s0 = (bi==0) ? sv.x : 0.f;
        const float s1 = (bi==1) ? sv.x : 0.f;
        const float s2 = (bi==2) ? sv.x : 0.f;
        const float s3 = (bi==3) ? sv.x : 0.f;
        const float* pr = &ld[he*384 + oc0*4];   // wave-uniform base
        #pragma unroll
        for (int j = 0; j < 24; ++j) {
            float4 p = *(const float4*)(pr + j*4);  // uniform-addr b128
            acc[j] = fmaf(p.x, s0, acc[j]);
            acc[j] = fmaf(p.y, s1, acc[j]);
            acc[j] = fmaf(p.z, s2, acc[j]);
            acc[j] = fmaf(p.w, s3, acc[j]);
        }
    }

    // epilogue: lane = n -> out[bb][oc][f1*8 + n>>3][f2*8 + (n&7)]
    const int r = lane >> 3, hh = lane & 7;
    const size_t ob = (size_t)bb*96*4096 + (size_t)(f1*8 + r)*64 + f2*8 + hh;
    #pragma unroll
    for (int j = 0; j < 24; ++j)
        out[ob + (size_t)(oc0 + j)*4096] = acc[j];
}

extern "C" void kernel_launch(void* const* d_in, const int* in_sizes, int n_in,
                              void* d_out, int out_size, void* d_ws, size_t ws_size,
                              hipStream_t stream) {
    (void)in_sizes; (void)n_in; (void)out_size; (void)ws_size;
    float* cd = (float*)d_ws;   // 1024 tiles x 4096 floats = 16 MiB
    cc_main<<<dim3(2048), dim3(TPB), 0, stream>>>(
        (const float*)d_in[0],  // x
        (const float*)d_in[1],  // Wf
        (const float*)d_in[2],  // bf
        (const float*)d_in[3],  // Wv
        (const float*)d_in[4],  // bv
        (const float*)d_in[5],  // Wp
        (const float*)d_in[7],  // sim_alpha
        (const float*)d_in[8],  // sim_beta
        cd);
    cc_comb<<<dim3(1024), dim3(TPB), 0, stream>>>(
        cd,
        (const float*)d_in[6],  // bp
        (float*)d_out);
}